// Round 4
// baseline (3462.553 us; speedup 1.0000x reference)
//
#include <hip/hip_runtime.h>
#include <hip/hip_bf16.h>

// Problem constants: B=16, T=512, E=1024, H=512, 3H=1536, E+H=1536.
//
// R9: stamped self-validating h exchange. R8 counters confirmed lstm_rec is
// exchange-latency-bound (7425 cy/step = drain RTT + tag visibility + poll +
// fetch RTT; MfmaUtil 0.64%). This round merges readiness into the data:
// h frames are u32 words = (step_stamp<<16)|bf16. Producer: 4 fire-and-forget
// dword stores (NO drain, NO tag). Consumer: optimistic 32x dwordx4 bulk fetch
// + per-word stamp check + retry. Detect+fetch collapse into ~1 RTT; the
// publish drain (~2000cy on every consumer's critical path) disappears.
// Ring depth 2 (exact-stamp match => overwrite of h(s) implies all waves
// finished step s => safe). 2 dirs x 2 slots x 32KB = 131072 B, exactly the
// verified HST region. Slot-1 stamps init'd to 0xFFFF (kills cross-replay
// stamp aliasing). Placement-free: no s_getreg, grid unchanged vs R8.

typedef __attribute__((ext_vector_type(8))) short s8v;
typedef __attribute__((ext_vector_type(4))) short s4v;
typedef __attribute__((ext_vector_type(4))) float f4v;
typedef __attribute__((ext_vector_type(4))) unsigned short us4;
typedef __attribute__((ext_vector_type(4))) unsigned int u4v;
typedef unsigned long long u64;
typedef unsigned int u32;

// ws layout (bytes) — ends at 76,677,120 <= R5/R8-verified 76,677,376
#define XBF_OFF   0ull          // 8192*1024*2        = 16,777,216
#define WXBF_OFF  16777216ull   // 3072*1024*2        =  6,291,456
#define WHBF_OFF  23068672ull   // 2*1536*512*2       =  3,145,728
#define XG_OFF    26214400ull   // 2*512*1536*16*2    = 50,331,648
#define HST_OFF   76546048ull   // 2 dirs * 2 slots * 32KB u32 frames = 131,072

static __device__ __forceinline__ short f2bf(float f) {
  __hip_bfloat16 h = __float2bfloat16(f);
  return *reinterpret_cast<short*>(&h);
}
static __device__ __forceinline__ float bf2f(unsigned short u) {
  union { unsigned int i; float f; } x;
  x.i = ((unsigned int)u) << 16;
  return x.f;
}
static __device__ __forceinline__ float sigmoidf_(float x) {
  return 1.0f / (1.0f + __expf(-x));
}
static __device__ __forceinline__ float tanhf_(float x) {
  return 1.0f - 2.0f / (1.0f + __expf(2.0f * x));
}

// ---- init: slot0 = h0 with stamp 0; slot1 = stamp 0xFFFF (invalid) -------
__global__ void init_state(const float* __restrict__ h0f, const float* __restrict__ h0b,
                           u32* __restrict__ hst) {
  int i = blockIdx.x * 256 + threadIdx.x;
  if (i < 2 * 16 * 512) {
    int dir = i >> 13;
    int r = i & 8191;       // b*512 + col
    int col = r & 511;
    const float* h0 = dir ? h0b : h0f;
    u32 v = (u32)(unsigned short)f2bf(h0[col]);     // stamp 0 in high half
    hst[(size_t)dir * 16384 + r] = v;               // slot 0
    hst[(size_t)dir * 16384 + 8192 + r] = 0xFFFF0000u;  // slot 1 invalid
  }
}

// ---------------- cast x to bf16 ----------------
__global__ void cast_x(const float* __restrict__ x, short* __restrict__ xb) {
  int i = (blockIdx.x * 256 + threadIdx.x) * 4;
  f4v v = *reinterpret_cast<const f4v*>(x + i);
  s4v o;
#pragma unroll
  for (int j = 0; j < 4; ++j) o[j] = f2bf(v[j]);
  *reinterpret_cast<s4v*>(xb + i) = o;
}

// ---------------- cast/split weights ----------------
__global__ void cast_w(const float* __restrict__ wf, const float* __restrict__ wb,
                       short* __restrict__ wxb, short* __restrict__ whb) {
  int e = blockIdx.x * 256 + threadIdx.x;  // < 1536*1536
  int dir = blockIdx.y;
  const float* w = dir ? wb : wf;
  int n = e / 1536;
  int k = e - n * 1536;
  short v = f2bf(w[e]);
  if (k < 1024)
    wxb[((size_t)(dir * 1536 + n)) * 1024 + k] = v;
  else
    whb[((size_t)(dir * 1536 + n)) * 512 + (k - 1024)] = v;
}

// ---------------- input GEMM: C = Xb @ Wxb^T, scattered to Xg[dir][t][ng][b] ----
__global__ __launch_bounds__(256) void gemm_in(const short* __restrict__ Xb,
                                               const short* __restrict__ Wxb,
                                               short* __restrict__ Xg) {
  __shared__ short As[128 * 72];
  __shared__ short Bs[128 * 72];
  int tid = threadIdx.x;
  int lane = tid & 63;
  int lr = lane & 15, quad = lane >> 4;
  int widx = tid >> 6;
  int wr = widx >> 1, wc = widx & 1;
  int bm = blockIdx.x, bn = blockIdx.y;

  f4v acc[4][4];
#pragma unroll
  for (int a = 0; a < 4; ++a)
#pragma unroll
    for (int b = 0; b < 4; ++b) acc[a][b] = {0.f, 0.f, 0.f, 0.f};

  const short* Arow = Xb + (size_t)bm * 128 * 1024;
  const short* Brow = Wxb + (size_t)bn * 128 * 1024;

  for (int kt = 0; kt < 16; ++kt) {
#pragma unroll
    for (int c = 0; c < 4; ++c) {
      int fl = c * 2048 + tid * 8;
      int row = fl >> 6, col = fl & 63;
      *reinterpret_cast<s8v*>(&As[row * 72 + col]) =
          *reinterpret_cast<const s8v*>(Arow + row * 1024 + kt * 64 + col);
      *reinterpret_cast<s8v*>(&Bs[row * 72 + col]) =
          *reinterpret_cast<const s8v*>(Brow + row * 1024 + kt * 64 + col);
    }
    __syncthreads();
#pragma unroll
    for (int kk = 0; kk < 2; ++kk) {
      s8v af[4], bfv[4];
#pragma unroll
      for (int mi = 0; mi < 4; ++mi)
        af[mi] = *reinterpret_cast<const s8v*>(&As[(wr * 64 + mi * 16 + lr) * 72 + kk * 32 + quad * 8]);
#pragma unroll
      for (int ni = 0; ni < 4; ++ni)
        bfv[ni] = *reinterpret_cast<const s8v*>(&Bs[(wc * 64 + ni * 16 + lr) * 72 + kk * 32 + quad * 8]);
#pragma unroll
      for (int mi = 0; mi < 4; ++mi)
#pragma unroll
        for (int ni = 0; ni < 4; ++ni)
          acc[mi][ni] = __builtin_amdgcn_mfma_f32_16x16x32_bf16(af[mi], bfv[ni], acc[mi][ni], 0, 0, 0);
    }
    __syncthreads();
  }

  int ngbase = bn * 128;
  int dir = (ngbase >= 1536) ? 1 : 0;
  int ng0 = ngbase - dir * 1536;
#pragma unroll
  for (int mi = 0; mi < 4; ++mi) {
#pragma unroll
    for (int ni = 0; ni < 4; ++ni) {
      int colg = ng0 + wc * 64 + ni * 16 + lr;
#pragma unroll
      for (int r = 0; r < 4; ++r) {
        int m = bm * 128 + wr * 64 + mi * 16 + quad * 4 + r;  // m = b*512 + t
        int b = m >> 9, t = m & 511;
        Xg[(((size_t)(dir * 512 + t)) * 1536 + colg) * 16 + b] = f2bf(acc[mi][ni][r]);
      }
    }
  }
}

// ---------------- recurrence ----------------
// 64 blocks x 64 threads (1 wave each); wave wg=blockIdx: dir=wg>>5, slice=wg&31.
// Wave owns h-cols [16*slice,16*slice+16). Wh in VGPRs. h exchanged through
// 2-slot u32 stamped ring: word = (stamp<<16)|bf16. Producer fire&forget;
// consumer optimistic fetch + stamp-verify + retry. All sc0sc1 (IF-served,
// placement-free).
__global__ __launch_bounds__(64, 1) void lstm_rec(
    const short* __restrict__ Whb, const short* __restrict__ Xg,
    const float* __restrict__ bfw, const float* __restrict__ bbw,
    const float* __restrict__ c0f, const float* __restrict__ c0b,
    u32* __restrict__ hst, float* __restrict__ out) {
  int lane = threadIdx.x & 63;
  int lr = lane & 15, quad = lane >> 4;
  int wg = blockIdx.x;
  int dir = wg >> 5;
  int slice = wg & 31;
  int col16 = slice * 16;

  // Persistent B fragments (normal cached loads)
  const short* Whd = Whb + (size_t)dir * 1536 * 512;
  s8v Bw[3][16];
#pragma unroll
  for (int g = 0; g < 3; ++g) {
    const short* rp = Whd + (size_t)(g * 512 + col16 + lr) * 512 + quad * 8;
#pragma unroll
    for (int k = 0; k < 16; ++k) Bw[g][k] = *reinterpret_cast<const s8v*>(rp + k * 32);
  }

  const float* bias = dir ? bbw : bfw;
  float bi = bias[col16 + lr];
  float bj = bias[512 + col16 + lr];
  float bo = bias[1024 + col16 + lr];

  const float* c0 = dir ? c0b : c0f;
  float cst[4];
  {
    float c0v = c0[col16 + lr];
#pragma unroll
    for (int r = 0; r < 4; ++r) cst[r] = c0v;
  }

  u32* hring = hst + (size_t)dir * 16384;  // 2 frames of [16 rows][512 cols] u32
  const short* xgbase = Xg + (size_t)dir * 512 * 1536 * 16;

  // First Xg prefetch (t for s=0)
  int t0 = dir ? 511 : 0;
  const short* xgp = xgbase + (size_t)t0 * 1536 * 16;
  us4 xiv = *reinterpret_cast<const us4*>(xgp + (col16 + lr) * 16 + quad * 4);
  us4 xjv = *reinterpret_cast<const us4*>(xgp + (512 + col16 + lr) * 16 + quad * 4);
  us4 xov = *reinterpret_cast<const us4*>(xgp + (1024 + col16 + lr) * 16 + quad * 4);

  for (int s = 0; s < 512; ++s) {
    int t = dir ? (511 - s) : s;
    u32 texp = (u32)s << 16;

    // --- optimistic bulk fetch + stamp verify + retry -----------------
    // lane reads row lr (stride 2048B), cols quad*8 + k*32 .. +8 (u32s):
    // chunk k = two dwordx4 at byte k*128 and k*128+16.
    const char* hp = (const char*)(hring + (size_t)(s & 1) * 8192) + lr * 2048 + quad * 32;
    u4v e[32];
    for (;;) {
      asm volatile(
          "global_load_dwordx4 %0, %16, off sc0 sc1\n\t"
          "global_load_dwordx4 %1, %16, off offset:16 sc0 sc1\n\t"
          "global_load_dwordx4 %2, %16, off offset:128 sc0 sc1\n\t"
          "global_load_dwordx4 %3, %16, off offset:144 sc0 sc1\n\t"
          "global_load_dwordx4 %4, %16, off offset:256 sc0 sc1\n\t"
          "global_load_dwordx4 %5, %16, off offset:272 sc0 sc1\n\t"
          "global_load_dwordx4 %6, %16, off offset:384 sc0 sc1\n\t"
          "global_load_dwordx4 %7, %16, off offset:400 sc0 sc1\n\t"
          "global_load_dwordx4 %8, %16, off offset:512 sc0 sc1\n\t"
          "global_load_dwordx4 %9, %16, off offset:528 sc0 sc1\n\t"
          "global_load_dwordx4 %10, %16, off offset:640 sc0 sc1\n\t"
          "global_load_dwordx4 %11, %16, off offset:656 sc0 sc1\n\t"
          "global_load_dwordx4 %12, %16, off offset:768 sc0 sc1\n\t"
          "global_load_dwordx4 %13, %16, off offset:784 sc0 sc1\n\t"
          "global_load_dwordx4 %14, %16, off offset:896 sc0 sc1\n\t"
          "global_load_dwordx4 %15, %16, off offset:912 sc0 sc1"
          : "=v"(e[0]), "=v"(e[1]), "=v"(e[2]), "=v"(e[3]), "=v"(e[4]),
            "=v"(e[5]), "=v"(e[6]), "=v"(e[7]), "=v"(e[8]), "=v"(e[9]),
            "=v"(e[10]), "=v"(e[11]), "=v"(e[12]), "=v"(e[13]), "=v"(e[14]),
            "=v"(e[15])
          : "v"(hp)
          : "memory");
      asm volatile(
          "global_load_dwordx4 %0, %16, off offset:1024 sc0 sc1\n\t"
          "global_load_dwordx4 %1, %16, off offset:1040 sc0 sc1\n\t"
          "global_load_dwordx4 %2, %16, off offset:1152 sc0 sc1\n\t"
          "global_load_dwordx4 %3, %16, off offset:1168 sc0 sc1\n\t"
          "global_load_dwordx4 %4, %16, off offset:1280 sc0 sc1\n\t"
          "global_load_dwordx4 %5, %16, off offset:1296 sc0 sc1\n\t"
          "global_load_dwordx4 %6, %16, off offset:1408 sc0 sc1\n\t"
          "global_load_dwordx4 %7, %16, off offset:1424 sc0 sc1\n\t"
          "global_load_dwordx4 %8, %16, off offset:1536 sc0 sc1\n\t"
          "global_load_dwordx4 %9, %16, off offset:1552 sc0 sc1\n\t"
          "global_load_dwordx4 %10, %16, off offset:1664 sc0 sc1\n\t"
          "global_load_dwordx4 %11, %16, off offset:1680 sc0 sc1\n\t"
          "global_load_dwordx4 %12, %16, off offset:1792 sc0 sc1\n\t"
          "global_load_dwordx4 %13, %16, off offset:1808 sc0 sc1\n\t"
          "global_load_dwordx4 %14, %16, off offset:1920 sc0 sc1\n\t"
          "global_load_dwordx4 %15, %16, off offset:1936 sc0 sc1\n\t"
          "s_waitcnt vmcnt(0)"
          : "=v"(e[16]), "=v"(e[17]), "=v"(e[18]), "=v"(e[19]), "=v"(e[20]),
            "=v"(e[21]), "=v"(e[22]), "=v"(e[23]), "=v"(e[24]), "=v"(e[25]),
            "=v"(e[26]), "=v"(e[27]), "=v"(e[28]), "=v"(e[29]), "=v"(e[30]),
            "=v"(e[31])
          : "v"(hp)
          : "memory");
      __builtin_amdgcn_sched_barrier(0);
      u32 diff = 0;
#pragma unroll
      for (int q = 0; q < 32; ++q) {
#pragma unroll
        for (int j = 0; j < 4; ++j) diff |= (e[q][j] ^ texp) & 0xFFFF0000u;
      }
      if (__ballot(diff == 0) == ~0ull) break;
    }

    // --- pack low halves into MFMA A fragments ---
    s8v av[16];
#pragma unroll
    for (int k = 0; k < 16; ++k) {
      u4v lo = e[2 * k], hi = e[2 * k + 1];
      u4v p;
      p[0] = (lo[0] & 0xFFFFu) | (lo[1] << 16);
      p[1] = (lo[2] & 0xFFFFu) | (lo[3] << 16);
      p[2] = (hi[0] & 0xFFFFu) | (hi[1] << 16);
      p[3] = (hi[2] & 0xFFFFu) | (hi[3] << 16);
      union { u4v u; s8v s; } cv;
      cv.u = p;
      av[k] = cv.s;
    }

    // --- MFMA: 48 x 16x16x32, acc in C-layout ---
    f4v a0 = {0.f, 0.f, 0.f, 0.f};
    f4v a1 = {0.f, 0.f, 0.f, 0.f};
    f4v a2 = {0.f, 0.f, 0.f, 0.f};
#pragma unroll
    for (int k = 0; k < 16; ++k) {
      a0 = __builtin_amdgcn_mfma_f32_16x16x32_bf16(av[k], Bw[0][k], a0, 0, 0, 0);
      a1 = __builtin_amdgcn_mfma_f32_16x16x32_bf16(av[k], Bw[1][k], a1, 0, 0, 0);
      a2 = __builtin_amdgcn_mfma_f32_16x16x32_bf16(av[k], Bw[2][k], a2, 0, 0, 0);
    }

    // --- elementwise (C-layout: row=quad*4+r, col=col16+lr) ---
    float hn[4];
    u32 hv[4];
    u32 st = ((u32)(s + 1)) << 16;
#pragma unroll
    for (int r = 0; r < 4; ++r) {
      float gi = a0[r] + bf2f(xiv[r]) + bi;
      float gj = a1[r] + bf2f(xjv[r]) + bj;
      float go = a2[r] + bf2f(xov[r]) + bo;
      float ii = sigmoidf_(gi);
      float jt = tanhf_(gj);
      float oo = sigmoidf_(go);
      cst[r] = (1.0f - ii) * cst[r] + ii * jt;
      hn[r] = tanhf_(cst[r]) * oo;
      hv[r] = st | (u32)(unsigned short)f2bf(hn[r]);
    }

    // --- publish: 4 stamped dword stores, fire-and-forget (no drain, no tag) ---
    {
      u32* hd0 = hring + (size_t)((s + 1) & 1) * 8192 + (quad * 4) * 512 + col16 + lr;
      u32* hd2 = hd0 + 1024;  // rows +2,+3 (2 rows * 512 u32)
      asm volatile(
          "global_store_dword %4, %0, off sc0 sc1\n\t"
          "global_store_dword %4, %1, off offset:2048 sc0 sc1\n\t"
          "global_store_dword %5, %2, off sc0 sc1\n\t"
          "global_store_dword %5, %3, off offset:2048 sc0 sc1"
          :: "v"(hv[0]), "v"(hv[1]), "v"(hv[2]), "v"(hv[3]), "v"(hd0), "v"(hd2)
          : "memory");
    }

    // --- off-critical-path: output store + next-step Xg prefetch ---
#pragma unroll
    for (int r = 0; r < 4; ++r)
      out[((size_t)(quad * 4 + r) * 512 + t) * 1024 + dir * 512 + col16 + lr] = hn[r];

    if (s < 511) {
      int tn = dir ? (511 - (s + 1)) : (s + 1);
      const short* xgn = xgbase + (size_t)tn * 1536 * 16;
      xiv = *reinterpret_cast<const us4*>(xgn + (col16 + lr) * 16 + quad * 4);
      xjv = *reinterpret_cast<const us4*>(xgn + (512 + col16 + lr) * 16 + quad * 4);
      xov = *reinterpret_cast<const us4*>(xgn + (1024 + col16 + lr) * 16 + quad * 4);
    }
  }
}

extern "C" void kernel_launch(void* const* d_in, const int* in_sizes, int n_in,
                              void* d_out, int out_size, void* d_ws, size_t ws_size,
                              hipStream_t stream) {
  const float* x    = (const float*)d_in[0];
  const float* wfw  = (const float*)d_in[1];
  const float* bfw  = (const float*)d_in[2];
  const float* wbw  = (const float*)d_in[3];
  const float* bbw  = (const float*)d_in[4];
  const float* h0f  = (const float*)d_in[5];
  const float* h0b  = (const float*)d_in[6];
  const float* c0f  = (const float*)d_in[7];
  const float* c0b  = (const float*)d_in[8];
  float* out = (float*)d_out;

  unsigned char* ws = (unsigned char*)d_ws;
  short* Xbf  = (short*)(ws + XBF_OFF);
  short* Wxbf = (short*)(ws + WXBF_OFF);
  short* Whbf = (short*)(ws + WHBF_OFF);
  short* Xg   = (short*)(ws + XG_OFF);
  u32*   hst  = (u32*)(ws + HST_OFF);

  init_state<<<64, 256, 0, stream>>>(h0f, h0b, hst);
  cast_x<<<8192, 256, 0, stream>>>(x, Xbf);
  cast_w<<<dim3(9216, 2), 256, 0, stream>>>(wfw, wbw, Wxbf, Whbf);
  gemm_in<<<dim3(64, 24), 256, 0, stream>>>(Xbf, Wxbf, Xg);
  lstm_rec<<<64, 64, 0, stream>>>(Whbf, Xg, bfw, bbw, c0f, c0b, hst, out);
}